// Round 8
// baseline (332.632 us; speedup 1.0000x reference)
//
#include <hip/hip_runtime.h>
#include <stdint.h>

#define DIM 4096
#define NH 32
#define NKV 8
#define HD 128
#define SEQ 2048
#define KVD 1024  // NKV*HD

typedef unsigned short u16;
typedef __attribute__((ext_vector_type(8))) short bf16x8;   // 8 bf16 in 4 VGPRs
typedef __attribute__((ext_vector_type(4))) float f32x4;

__device__ __forceinline__ float bf2f(u16 v){
  union { unsigned u; float f; } c; c.u = ((unsigned)v) << 16; return c.f;
}
__device__ __forceinline__ u16 f2bf(float f){
  union { float f; unsigned u; } c; c.f = f;
  unsigned u = c.u;
  u += 0x7FFF + ((u >> 16) & 1);   // RNE
  return (u16)(u >> 16);
}
__device__ __forceinline__ unsigned pack2bf(float a, float b){
  return (unsigned)f2bf(a) | ((unsigned)f2bf(b) << 16);
}

__device__ __forceinline__ void gl_lds16(const void* g, void* l){
  __builtin_amdgcn_global_load_lds((const __attribute__((address_space(1))) void*)g,
                                   (__attribute__((address_space(3))) void*)l, 16, 0, 0);
}

#define VM2 asm volatile("s_waitcnt vmcnt(2)" ::: "memory")
#define VM0 asm volatile("s_waitcnt vmcnt(0)" ::: "memory")
#define LGKM0 asm volatile("s_waitcnt lgkmcnt(0)" ::: "memory")
#define SB0 __builtin_amdgcn_sched_barrier(0)
#define BAR __builtin_amdgcn_s_barrier()

// ---------------- fused fp32 -> bf16 conversion (one launch, 5 segments) -----
__global__ void cvt_all(const float* __restrict__ x,  const float* __restrict__ wq,
                        const float* __restrict__ wk, const float* __restrict__ wv,
                        const float* __restrict__ wo,
                        u16* __restrict__ xb,  u16* __restrict__ wqb,
                        u16* __restrict__ wkb, u16* __restrict__ wvb,
                        u16* __restrict__ wob){
  const int b = blockIdx.x;
  const float* in; u16* out; int base;
  if      (b <  8192){ in = x;  out = xb;  base = b; }
  else if (b < 24576){ in = wq; out = wqb; base = b - 8192; }
  else if (b < 28672){ in = wk; out = wkb; base = b - 24576; }
  else if (b < 32768){ in = wv; out = wvb; base = b - 28672; }
  else               { in = wo; out = wob; base = b - 32768; }
  const int i = (base*256 + threadIdx.x)*4;
  float4 v = *(const float4*)(in + i);
  ushort4 o;
  o.x = f2bf(v.x); o.y = f2bf(v.y); o.z = f2bf(v.z); o.w = f2bf(v.w);
  *(ushort4*)(out + i) = o;
}

// ---------------- out += partial (f32x4, exact grid) --------------------------
__global__ void add_f32(float* __restrict__ out, const float* __restrict__ p){
  const int i = blockIdx.x*256 + threadIdx.x;
  float4 a = ((const float4*)out)[i];
  const float4 b = ((const float4*)p)[i];
  a.x += b.x; a.y += b.y; a.z += b.z; a.w += b.w;
  ((float4*)out)[i] = a;
}

// ---------------- 256x256 quadrant-rotation pipelined NT GEMM -----------------
// BM=BN=256, BK=64, 8 waves (2x4), wave owns 128x64. 128 KB dbuf LDS.
// Per K-tile: 4 phases in quadrant order (M0N0),(M0N1),(M1N1),(M1N0); B-frags
// register-held across the tile. Phase = { ds_reads(top) ; stage ONE unit ->
// buf^1 ; [VM2 @P1/P4] ; BAR ; lgkm0+SB0 ; setprio'd 16 MFMA ; BAR }.
//
// Staging uses ABSOLUTE tile rows for both global src and LDS dest:
//   stA(rowbase): rows rowbase..rowbase+127 at dstbuf + row*128 (dstbuf = A-buf
//   base). stB(u): the 128 rows with (row&32)==u*32 (bit5 interleave - exactly
//   the rows RDB(u) reads across all waves), at dstbuf + row*128 (B-buf base).
//   (R7 bug: stA call sites double-added +16384; LDS dest must be buffer base.)
// Guarantee chain: P4(t-1) stages B-unit1(t) then {VM2;BAR} -> at P1(t) only
//   B-unit1(t) in flight; P1 reads A(t) rows (staged P1/P2(t-1), drained) and
//   B-unit0(t) (staged P3(t-1), drained). P1 stages A0(t+1), {VM2;BAR} drains
//   B-unit1(t) (leaves A0(t+1)) -> P2's RDB(1) safe. P3's RDA(1) rows drained
//   long before. P4 reads nothing. Last tile: VM0 at P1.
// EPI 0: fused QKV, B=[wq;wk;wv] [6144][4096]; grid 8bm x 24bn = 192 (XCD owns
//        one bm -> A-panel L2-resident). Epilogue routes per 16-col frag.
// EPI 1: O-proj split-K=2, f32 partials; grid 8bm x 2ks x 16bn = 256.
template<int EPI>
__global__ __launch_bounds__(512, 2) void gemmQ(const u16* __restrict__ A,
    const u16* __restrict__ B, void* __restrict__ C0, void* __restrict__ C1,
    void* __restrict__ C2, const float* __restrict__ rf, float* __restrict__ Cp){
  __shared__ __align__(16) char lds[131072];   // A: [2][256][128B] | B at +65536
  const int t = threadIdx.x, w = t >> 6, l = t & 63;
  const int lg = l >> 4, li = l & 15;
  const int wr = w >> 2, wc = w & 3;
  int bm, bn, kbase, nt, ks = 0;
  if (EPI == 0){
    const int idx = ((int)blockIdx.x & 7)*24 + ((int)blockIdx.x >> 3);  // nwg=192
    bm = idx / 24; bn = idx % 24; kbase = 0; nt = 64;                   // XCD->bm
  } else {
    const int idx = ((int)blockIdx.x & 7)*32 + ((int)blockIdx.x >> 3);  // nwg=256
    bm = idx >> 5; ks = (idx >> 4) & 1; bn = idx & 15; kbase = ks*2048; nt = 32;
  }
  const u16* Ab = A + (size_t)bm*256*DIM;
  const u16* Bb = B + (size_t)bn*256*DIM;

  // stage A half (absolute rows rowbase..rowbase+127) into A-buf base dstbuf
  auto stA = [&](int rowbase, int kabs, char* dstbuf){
    #pragma unroll
    for (int j = 0; j < 2; ++j){
      const int rl = rowbase + j*64 + (t >> 3);
      gl_lds16(Ab + (size_t)rl*DIM + kabs + (((t & 7) ^ (rl & 7)) << 3),
               dstbuf + rl*128 + (t & 7)*16);
    }
  };
  // stage B unit u = the 128 rows with (row&32)==u*32, into B-buf base dstbuf
  auto stB = [&](int u, int kabs, char* dstbuf){
    #pragma unroll
    for (int j = 0; j < 2; ++j){
      const int m = j*64 + (t >> 3);                     // 0..127
      const int row = ((m >> 5) << 6) + u*32 + (m & 31); // wave-uniform + (l>>3)
      gl_lds16(Bb + (size_t)row*DIM + kabs + (((t & 7) ^ (row & 7)) << 3),
               dstbuf + row*128 + (t & 7)*16);
    }
  };

  f32x4 acc[8][4] = {};

#define RDA(ms) { _Pragma("unroll") \
    for (int i2 = 0; i2 < 4; ++i2){ \
      const int R = wr*128 + (ms)*64 + i2*16 + li; \
      a_[i2][0] = *(const bf16x8*)(ldsA + R*128 + (( lg    ^ (R & 7)) << 4)); \
      a_[i2][1] = *(const bf16x8*)(ldsA + R*128 + (((lg+4) ^ (R & 7)) << 4)); } }
#define RDB(ns, bv) { _Pragma("unroll") \
    for (int j2 = 0; j2 < 2; ++j2){ \
      const int R = wc*64 + (ns)*32 + j2*16 + li; \
      bv[j2][0] = *(const bf16x8*)(ldsB + R*128 + (( lg    ^ (R & 7)) << 4)); \
      bv[j2][1] = *(const bf16x8*)(ldsB + R*128 + (((lg+4) ^ (R & 7)) << 4)); } }
#define MM16(ms, ns, bv) { \
    __builtin_amdgcn_s_setprio(1); \
    _Pragma("unroll") \
    for (int i2 = 0; i2 < 4; ++i2) \
      _Pragma("unroll") \
      for (int j2 = 0; j2 < 2; ++j2){ \
        acc[(ms)*4+i2][(ns)*2+j2] = __builtin_amdgcn_mfma_f32_16x16x32_bf16(a_[i2][0], bv[j2][0], acc[(ms)*4+i2][(ns)*2+j2], 0, 0, 0); \
        acc[(ms)*4+i2][(ns)*2+j2] = __builtin_amdgcn_mfma_f32_16x16x32_bf16(a_[i2][1], bv[j2][1], acc[(ms)*4+i2][(ns)*2+j2], 0, 0, 0); } \
    __builtin_amdgcn_s_setprio(0); }

  // prologue: stage tile 0; B-unit1 staged last, left in flight by VM2
  stA(  0, kbase, lds);
  stA(128, kbase, lds);
  stB(0, kbase, lds + 65536);
  stB(1, kbase, lds + 65536);
  VM2; BAR;

  for (int tt = 0; tt < nt; ++tt){
    const int buf = tt & 1, b2 = buf ^ 1;
    const char* ldsA = lds + buf*32768;
    const char* ldsB = lds + 65536 + buf*32768;
    char* ldsA2 = lds + b2*32768;
    char* ldsB2 = lds + 65536 + b2*32768;
    const int k1 = kbase + (tt+1)*64;
    const bool pf = (tt + 1 < nt);
    bf16x8 a_[4][2], bN0[2][2], bN1[2][2];

    // P1: quadrant M0xN0 (reads A rows wr*128+0..63 + B-unit0 - both landed)
    RDA(0); RDB(0, bN0);
    if (pf){ stA(0, k1, ldsA2); VM2; } else { VM0; }
    BAR; LGKM0; SB0;
    MM16(0, 0, bN0);
    BAR;
    // P2: quadrant M0xN1 (reads B-unit1, guaranteed by P1's VM2+BAR)
    RDB(1, bN1);
    if (pf) stA(128, k1, ldsA2);
    BAR; LGKM0; SB0;
    MM16(0, 1, bN1);
    BAR;
    // P3: quadrant M1xN1 (reads A rows wr*128+64..127 - staged t-1, drained)
    RDA(1);
    if (pf) stB(0, k1, ldsB2);
    BAR; LGKM0; SB0;
    MM16(1, 1, bN1);
    BAR;
    // P4: quadrant M1xN0 (all operands register-held)
    if (pf){ stB(1, k1, ldsB2); VM2; }
    BAR; SB0;
    MM16(1, 0, bN0);
    BAR;
  }
#undef RDA
#undef RDB
#undef MM16

  // ---------------- epilogue ----------------
  if (EPI == 1){
    float* C = (float*)(ks ? Cp : C0);
    #pragma unroll
    for (int i = 0; i < 8; ++i){
      const int srow = bm*256 + wr*128 + (i >> 2)*64 + (i & 3)*16 + lg*4;
      #pragma unroll
      for (int j = 0; j < 4; ++j){
        const int col = bn*256 + wc*64 + (j >> 1)*32 + (j & 1)*16 + li;
        #pragma unroll
        for (int r = 0; r < 4; ++r)
          C[(size_t)(srow + r)*DIM + col] = acc[i][j][r];
      }
    }
  } else {
    #pragma unroll
    for (int i = 0; i < 8; ++i){
      const int srow0 = bm*256 + wr*128 + (i >> 2)*64 + (i & 3)*16 + lg*4;
      #pragma unroll
      for (int j = 0; j < 4; ++j){
        const int col = bn*256 + wc*64 + (j >> 1)*32 + (j & 1)*16 + li;
        const int fc0 = col - li;                       // 16-aligned frag base
        if (fc0 < 5120){                  // Q (cols<4096) or K: fused RoPE
          u16* C  = (fc0 < 4096) ? (u16*)C0 : (u16*)C1;
          const int ldc  = (fc0 < 4096) ? DIM : KVD;
          const int ccol = (fc0 < 4096) ? col : col - 4096;
          const int i4 = ((col & 127) >> 1) << 2;       // head-rel pos (128-aligned)
          #pragma unroll
          for (int r = 0; r < 4; ++r){
            const float v = acc[i][j][r];
            const float p = __shfl_xor(v, 1);           // partner col (li^1)
            const int srow = srow0 + r;
            const float cs = rf[(size_t)srow*256 + i4];
            const float sn = rf[(size_t)srow*256 + i4 + 1];
            const float o = (col & 1) ? (v*cs + p*sn) : (v*cs - p*sn);
            C[(size_t)srow*ldc + ccol] = f2bf(o);
          }
        } else {                          // V -> transposed write Vt[1024][2048]
          u16* C = (u16*)C2;
          ushort4 o;
          o.x = f2bf(acc[i][j][0]); o.y = f2bf(acc[i][j][1]);
          o.z = f2bf(acc[i][j][2]); o.w = f2bf(acc[i][j][3]);
          *(ushort4*)&C[(size_t)(col - 5120)*SEQ + srow0] = o;
        }
      }
    }
  }
}

// ---------------- causal GQA flash attention ---------------------------------
// 1D grid 1024, longest-qt blocks first: qt = 31 - bid/32, h = bid%32.
// 4 waves; wave w owns q rows [qt*64+16w, +16). Swapped QK^T (mfma(K,Q)) so
// each lane owns one full q-row (q = li): in-lane softmax + 2-shfl reduce.
// K/V double-buffered in LDS, next tile staged before compute (2-phase T3).
__global__ __launch_bounds__(256) void flash_attn(const u16* __restrict__ Q,
                                                  const u16* __restrict__ Kg,
                                                  const u16* __restrict__ Vt,
                                                  u16* __restrict__ O){
  __shared__ bf16x8 smK[2][64*16];              // [64 rows][16 slots], swizzled; 2x16KB
  __shared__ bf16x8 smV[2][128*8];              // [128 rows][8 slots], swizzled; 2x16KB
  __shared__ __align__(16) u16 smP[4][16*64];   // per-wave P, XOR-swizzled 16B chunks; 8KB
  const int bid = blockIdx.x;
  const int h  = bid & 31;
  const int qt = 31 - (bid >> 5);
  const int g  = h >> 2;
  const int t = threadIdx.x, w = t >> 6, l = t & 63;
  const int lg = l >> 4, li = l & 15;

  bf16x8 qf[4];                                  // Q row (w*16+li), d-chunks
  {
    const u16* qrow = Q + (size_t)(qt*64 + w*16 + li)*DIM + h*HD;
    #pragma unroll
    for (int kc = 0; kc < 4; ++kc)
      qf[kc] = *(const bf16x8*)(qrow + kc*32 + lg*8);
  }
  f32x4 accO[8] = {};
  float mrun = -1e30f, lsum = 0.f;
  const float SC = 0.08838834764831845f * 1.4426950408889634f;  // scale * log2(e)

  const int ksrow = t >> 4, ksslot = t & 15;  // K staging: 256B rows, 16 slots
  const int vsrow = t >> 3, vsslot = t & 7;   // V staging: 128B rows, 8 slots

  auto stage = [&](int kt, int b){
    #pragma unroll
    for (int j = 0; j < 4; ++j){
      const int krow = j*16 + ksrow;
      const int ksl = (ksslot & 8) | ((ksslot ^ (krow & 7)) & 7);
      gl_lds16(Kg + (size_t)(kt*64 + krow)*KVD + g*HD + ksl*8, (char*)&smK[b][0] + j*4096 + w*1024);
      const int vrow = j*32 + vsrow;
      const int vsl = (vsslot ^ (vrow & 7)) & 7;
      gl_lds16(Vt + (size_t)(g*HD + vrow)*SEQ + kt*64 + vsl*8, (char*)&smV[b][0] + j*4096 + w*1024);
    }
  };

  stage(0, 0);
  int buf = 0;
  u16* pw = &smP[w][0];

  for (int kt = 0; kt <= qt; ++kt){
    __syncthreads();                      // implicit vmcnt(0): tile-kt stage done
    if (kt < qt) stage(kt + 1, buf ^ 1);  // overlap next stage with this compute

    // S^T = K Q^T : lane holds S[kk = nj*16+lg*4+r][q = li]
    f32x4 sacc[4] = {};
    #pragma unroll
    for (int kc = 0; kc < 4; ++kc){
      #pragma unroll
      for (int nj = 0; nj < 4; ++nj){
        const int R = nj*16 + li;
        int sl = lg + 4*kc;
        sl = (sl & 8) | ((sl ^ (R & 7)) & 7);
        sacc[nj] = __builtin_amdgcn_mfma_f32_16x16x32_bf16(smK[buf][R*16 + sl], qf[kc], sacc[nj], 0, 0, 0);
      }
    }
    float p[4][4];
    #pragma unroll
    for (int nj = 0; nj < 4; ++nj)
      #pragma unroll
      for (int r = 0; r < 4; ++r)
        p[nj][r] = sacc[nj][r] * SC;
    if (kt == qt){                         // mask only on the diagonal tile
      const int qloc = w*16 + li;
      #pragma unroll
      for (int nj = 0; nj < 4; ++nj)
        #pragma unroll
        for (int r = 0; r < 4; ++r)
          if (nj*16 + lg*4 + r > qloc) p[nj][r] = -1e30f;
    }
    // online softmax, row q=li fully in this lane (16 vals) + lanes l^16,l^32
    float mx = p[0][0];
    #pragma unroll
    for (int nj = 0; nj < 4; ++nj)
      #pragma unroll
      for (int r = 0; r < 4; ++r) mx = fmaxf(mx, p[nj][r]);
    mx = fmaxf(mx, __shfl_xor(mx, 16));
    mx = fmaxf(mx, __shfl_xor(mx, 32));
    const float mnew = fmaxf(mrun, mx);
    const float alpha = exp2f(mrun - mnew);
    float s = 0.f;
    #pragma unroll
    for (int nj = 0; nj < 4; ++nj)
      #pragma unroll
      for (int r = 0; r < 4; ++r){ p[nj][r] = exp2f(p[nj][r] - mnew); s += p[nj][r]; }
    s += __shfl_xor(s, 16);
    s += __shfl_xor(s, 32);
    lsum = lsum * alpha + s;
    mrun = mnew;
    // broadcast alpha to accO's rows (q = lg*4+r held by lane li' = lg*4+r)
    float al[4];
    #pragma unroll
    for (int r = 0; r < 4; ++r) al[r] = __shfl(alpha, (l & 48) | (lg*4 + r));
    #pragma unroll
    for (int dj = 0; dj < 8; ++dj)
      #pragma unroll
      for (int r = 0; r < 4; ++r) accO[dj][r] *= al[r];
    // write P (row q=li, kk consecutive per write): 4x 8B swizzled ds_write
    #pragma unroll
    for (int nj = 0; nj < 4; ++nj){
      const int c = nj*2 + (lg >> 1);
      uint2 v; v.x = pack2bf(p[nj][0], p[nj][1]); v.y = pack2bf(p[nj][2], p[nj][3]);
      *(uint2*)((char*)pw + li*128 + ((c ^ (li & 7)) << 4) + ((lg & 1) << 3)) = v;
    }
    // O += P V   (A-frag: P row li, kk = kc2*32+lg*8+j; B-frag: Vt row d)
    #pragma unroll
    for (int kc2 = 0; kc2 < 2; ++kc2){
      const bf16x8 pf = *(const bf16x8*)((char*)pw + li*128 + (((kc2*4 + lg) ^ (li & 7)) << 4));
      #pragma unroll
      for (int dj = 0; dj < 8; ++dj){
        const int R = dj*16 + li;
        const bf16x8 vf = smV[buf][R*8 + ((lg + 4*kc2) ^ (R & 7))];
        accO[dj] = __builtin_amdgcn_mfma_f32_16x16x32_bf16(pf, vf, accO[dj], 0, 0, 0);
      }
    }
    buf ^= 1;
  }
  // epilogue: divide by row sum (row q=lg*4+r), write
  float linv[4];
  #pragma unroll
  for (int r = 0; r < 4; ++r) linv[r] = 1.f / __shfl(lsum, (l & 48) | (lg*4 + r));
  #pragma unroll
  for (int dj = 0; dj < 8; ++dj)
    #pragma unroll
    for (int r = 0; r < 4; ++r)
      O[(size_t)(qt*64 + w*16 + lg*4 + r)*DIM + h*HD + dj*16 + li] = f2bf(accO[dj][r] * linv[r]);
}

// -----------------------------------------------------------------------------
extern "C" void kernel_launch(void* const* d_in, const int* in_sizes, int n_in,
                              void* d_out, int out_size, void* d_ws, size_t ws_size,
                              hipStream_t stream){
  const float* x  = (const float*)d_in[0];
  const float* wq = (const float*)d_in[1];
  const float* wk = (const float*)d_in[2];
  const float* wv = (const float*)d_in[3];
  const float* wo = (const float*)d_in[4];
  const float* rf = (const float*)d_in[5];
  // d_in[6] = start_pos (unused by the reference)
  float* out = (float*)d_out;

  char* ws = (char*)d_ws;
  size_t off = 0;
  auto alloc = [&](size_t nbytes){ void* p = ws + off; off += (nbytes + 255) & ~(size_t)255; return p; };
  u16* xb  = (u16*)alloc((size_t)SEQ*DIM*2);
  u16* wqb = (u16*)alloc((size_t)DIM*DIM*2);   // wqb/wkb/wvb contiguous => B[6144][4096]
  u16* wkb = (u16*)alloc((size_t)KVD*DIM*2);
  u16* wvb = (u16*)alloc((size_t)KVD*DIM*2);
  u16* wob = (u16*)alloc((size_t)DIM*DIM*2);
  u16* Qb  = (u16*)alloc((size_t)SEQ*DIM*2);
  u16* K8  = (u16*)alloc((size_t)SEQ*KVD*2);
  u16* Vtr = (u16*)alloc((size_t)KVD*SEQ*2);
  u16* AO  = (u16*)alloc((size_t)SEQ*DIM*2);
  float* P1 = (float*)wqb;   // reuse: wqb is dead after the QKV GEMM (32 MB)

  cvt_all<<<49152, 256, 0, stream>>>(x, wq, wk, wv, wo, xb, wqb, wkb, wvb, wob);

  // Fused QKV projection + RoPE + V^T (192 blocks = 8bm x 24bn, BM=BN=256)
  gemmQ<0><<<192, 512, 0, stream>>>(xb, wqb, Qb, K8, Vtr, rf, nullptr);

  flash_attn<<<SEQ/64 * NH, 256, 0, stream>>>(Qb, K8, Vtr, AO);

  // O projection, split-K=2 (256 blocks = 8bm x 2ks x 16bn)
  gemmQ<1><<<256, 512, 0, stream>>>(AO, wob, out, nullptr, nullptr, nullptr, P1);
  add_f32<<<8192, 256, 0, stream>>>(out, P1);
}

// Round 9
// 310.460 us; speedup vs baseline: 1.0714x; 1.0714x over previous
//
#include <hip/hip_runtime.h>
#include <stdint.h>

#define DIM 4096
#define NH 32
#define NKV 8
#define HD 128
#define SEQ 2048
#define KVD 1024  // NKV*HD

typedef unsigned short u16;
typedef __attribute__((ext_vector_type(8))) short bf16x8;   // 8 bf16 in 4 VGPRs
typedef __attribute__((ext_vector_type(4))) float f32x4;

__device__ __forceinline__ float bf2f(u16 v){
  union { unsigned u; float f; } c; c.u = ((unsigned)v) << 16; return c.f;
}
__device__ __forceinline__ u16 f2bf(float f){
  union { float f; unsigned u; } c; c.f = f;
  unsigned u = c.u;
  u += 0x7FFF + ((u >> 16) & 1);   // RNE
  return (u16)(u >> 16);
}
__device__ __forceinline__ unsigned pack2bf(float a, float b){
  return (unsigned)f2bf(a) | ((unsigned)f2bf(b) << 16);
}

__device__ __forceinline__ void gl_lds16(const void* g, void* l){
  __builtin_amdgcn_global_load_lds((const __attribute__((address_space(1))) void*)g,
                                   (__attribute__((address_space(3))) void*)l, 16, 0, 0);
}

#define VM4 asm volatile("s_waitcnt vmcnt(4)" ::: "memory")
#define VM3 asm volatile("s_waitcnt vmcnt(3)" ::: "memory")
#define VM2 asm volatile("s_waitcnt vmcnt(2)" ::: "memory")
#define VM0 asm volatile("s_waitcnt vmcnt(0)" ::: "memory")
#define LGKM0 asm volatile("s_waitcnt lgkmcnt(0)" ::: "memory")
#define SB0 __builtin_amdgcn_sched_barrier(0)
#define BAR __builtin_amdgcn_s_barrier()

// ---------------- fused fp32 -> bf16 conversion (one launch, 5 segments) -----
__global__ void cvt_all(const float* __restrict__ x,  const float* __restrict__ wq,
                        const float* __restrict__ wk, const float* __restrict__ wv,
                        const float* __restrict__ wo,
                        u16* __restrict__ xb,  u16* __restrict__ wqb,
                        u16* __restrict__ wkb, u16* __restrict__ wvb,
                        u16* __restrict__ wob){
  const int b = blockIdx.x;
  const float* in; u16* out; int base;
  if      (b <  8192){ in = x;  out = xb;  base = b; }
  else if (b < 24576){ in = wq; out = wqb; base = b - 8192; }
  else if (b < 28672){ in = wk; out = wkb; base = b - 24576; }
  else if (b < 32768){ in = wv; out = wvb; base = b - 28672; }
  else               { in = wo; out = wob; base = b - 32768; }
  const int i = (base*256 + threadIdx.x)*4;
  float4 v = *(const float4*)(in + i);
  ushort4 o;
  o.x = f2bf(v.x); o.y = f2bf(v.y); o.z = f2bf(v.z); o.w = f2bf(v.w);
  *(ushort4*)(out + i) = o;
}

// ---------------- out += partial (f32x4, exact grid) --------------------------
__global__ void add_f32(float* __restrict__ out, const float* __restrict__ p){
  const int i = blockIdx.x*256 + threadIdx.x;
  float4 a = ((const float4*)out)[i];
  const float4 b = ((const float4*)p)[i];
  a.x += b.x; a.y += b.y; a.z += b.z; a.w += b.w;
  ((float4*)out)[i] = a;
}

// ---------------- m201-style 4-phase pipelined NT GEMM ------------------------
// BM=256, BN=BUNITS*64 (192 or 256), BK=64, 8 waves (2x4), dbuf LDS, 1-tile
// prefetch. Phase = { ds_read frags ; [wait] ; stages -> buf^1 ; [wait] ; BAR ;
// lgkm0+SB0 ; setprio'd MFMA ; BAR }.
//
// WAIT SLACK DISCIPLINE (R9): every vmcnt waits only for loads issued >=2
// phases earlier. Unit consumption: P0/P1 read A-units {0,2} + ALL B (B-frags
// preloaded at P0); P2/P3 read A-units {1,3}. Invariant: {A1,A3} of the
// current tile are the only loads left in flight at tile start.
//   P0: stage B0,B1,B2[,B3 at P1 for BUNITS=4]
//   P1: VM3 (drains prev A1,A3 - issued P2/P3 of prev tile, 2-3 phases old)
//       then stage [B3,] A0, A2
//   P2: stage A1
//   P3: stage A3; VM2 (drains through A2, issued P1 - 2 phases old;
//       leaves {A1,A3} - exactly P0/P1(next)'s non-needs)
// Outstanding-count check (BUNITS=3): P1-wait: {A1,A3}+{B0,B1,B2}=5 -> VM3
// drains 2 oldest = A1,A3. P3-wait: 7 issued -> VM2 drains 5 oldest =
// B0,B1,B2,A0,A2 (exactly P0/P1(next) needs). BUNITS=4: P1-wait: 2+3=5 -> VM3;
// P3-wait: 8 -> VM2 drains 6 = B0..B3,A0,A2. Last tile: P1 VM0; P3 none.
// Prologue stages all units with A1,A3 LAST, then VM2 -> same invariant.
// EPI 0 (BUNITS=3): fused QKV, B = [wq;wk;wv] contiguous [6144][4096];
//   epilogue routes per 16-col frag: Q+RoPE / K+RoPE / V^T. grid 8x32=256.
// EPI 1 (BUNITS=4): O-proj split-K=2, f32 partials. grid 8x2x16=256.
template<int BUNITS, int EPI>
__global__ __launch_bounds__(512, 2) void gemmP(const u16* __restrict__ A,
    const u16* __restrict__ B, void* __restrict__ C0, void* __restrict__ C1,
    void* __restrict__ C2, const float* __restrict__ rf, float* __restrict__ Cp){
  constexpr int BN = BUNITS*64;
  __shared__ __align__(16) char lds[65536 + BUNITS*16384];  // A[2][256][128B] | B[2][BN][128B]
  const int t = threadIdx.x, w = t >> 6, l = t & 63;
  const int lg = l >> 4, li = l & 15;
  const int wr = w >> 2, wc = w & 3;
  const int idx = ((int)blockIdx.x & 7)*32 + ((int)blockIdx.x >> 3);  // XCD swizzle (nwg=256)

  int bm, bn, kbase, nt, ks = 0;
  if (EPI == 0){ bm = idx & 7; bn = idx >> 3; kbase = 0; nt = 64; }
  else         { bm = idx & 7; ks = (idx >> 3) & 1; bn = idx >> 4; kbase = ks*2048; nt = 32; }
  const u16* Ab = A + (size_t)bm*256*DIM;
  const u16* Bb = B + (size_t)bn*BN*DIM;

  // stage one 64-row x 128B unit: 1 load/thread (512 x 16B = 8KB)
  auto stA = [&](int k0, int abase, int u){
    const int r = u*64 + (t >> 3);
    gl_lds16(Ab + (size_t)r*DIM + k0 + (((t & 7) ^ (r & 7)) << 3),
             lds + abase + u*8192 + (t >> 3)*128 + (t & 7)*16);
  };
  auto stB = [&](int k0, int bbase, int u){
    const int r = u*64 + (t >> 3);
    gl_lds16(Bb + (size_t)r*DIM + k0 + (((t & 7) ^ (r & 7)) << 3),
             lds + bbase + u*8192 + (t >> 3)*128 + (t & 7)*16);
  };

  f32x4 acc[8][BUNITS] = {};
  bf16x8 bfr[BUNITS][2];   // B-frags held across all 4 phases of a tile

// phase p: ds_read m-frags 2p,2p+1 (+ all B at p==0); then __VA_ARGS__ (waits
// + stages in the stated order); then BAR ; lgkm0 ; pinned setprio'd MFMA ; BAR.
#define PH(p, ...) { \
    bf16x8 af[2][2]; \
    _Pragma("unroll") \
    for (int q = 0; q < 2; ++q){ \
      const int R = wr*128 + (2*(p)+q)*16 + li; \
      af[q][0] = *(const bf16x8*)(ldsA + R*128 + (( lg    ^ (R & 7)) << 4)); \
      af[q][1] = *(const bf16x8*)(ldsA + R*128 + (((lg+4) ^ (R & 7)) << 4)); \
    } \
    if ((p) == 0){ \
      _Pragma("unroll") \
      for (int j = 0; j < BUNITS; ++j){ \
        const int R = wc*(BUNITS*16) + j*16 + li; \
        bfr[j][0] = *(const bf16x8*)(ldsB + R*128 + (( lg    ^ (R & 7)) << 4)); \
        bfr[j][1] = *(const bf16x8*)(ldsB + R*128 + (((lg+4) ^ (R & 7)) << 4)); \
      } \
    } \
    __VA_ARGS__; \
    BAR; LGKM0; SB0; \
    __builtin_amdgcn_s_setprio(1); \
    _Pragma("unroll") \
    for (int q = 0; q < 2; ++q) \
      _Pragma("unroll") \
      for (int j = 0; j < BUNITS; ++j){ \
        acc[2*(p)+q][j] = __builtin_amdgcn_mfma_f32_16x16x32_bf16(af[q][0], bfr[j][0], acc[2*(p)+q][j], 0, 0, 0); \
        acc[2*(p)+q][j] = __builtin_amdgcn_mfma_f32_16x16x32_bf16(af[q][1], bfr[j][1], acc[2*(p)+q][j], 0, 0, 0); \
      } \
    __builtin_amdgcn_s_setprio(0); \
    BAR; }

  // prologue: stage tile 0 with A1,A3 LAST; VM2 leaves {A1,A3} (the invariant)
  #pragma unroll
  for (int u = 0; u < BUNITS; ++u) stB(kbase, 65536, u);
  stA(kbase, 0, 0); stA(kbase, 0, 2);
  stA(kbase, 0, 1); stA(kbase, 0, 3);
  VM2; BAR;

  for (int tt = 0; tt < nt; ++tt){
    const int buf = tt & 1, b2 = buf ^ 1;
    const int k1 = kbase + (tt+1)*64;
    const bool pf = (tt + 1 < nt);
    const char* ldsA = lds + buf*32768;
    const char* ldsB = lds + 65536 + buf*BUNITS*8192;
    const int a2 = b2*32768, b2o = 65536 + b2*BUNITS*8192;

    PH(0, if (pf){ stB(k1, b2o, 0); stB(k1, b2o, 1); stB(k1, b2o, 2); })
    PH(1, if (pf){ VM3; if constexpr (BUNITS == 4) stB(k1, b2o, 3);
                   stA(k1, a2, 0); stA(k1, a2, 2); }
          else   { VM0; })
    PH(2, if (pf){ stA(k1, a2, 1); })
    PH(3, if (pf){ stA(k1, a2, 3); VM2; })
  }
#undef PH

  // ---------------- epilogue ----------------
  if (EPI == 1){
    float* C = (float*)(ks ? Cp : C0);
    #pragma unroll
    for (int i = 0; i < 8; ++i){
      const int srow = bm*256 + wr*128 + i*16 + lg*4;
      #pragma unroll
      for (int j = 0; j < BUNITS; ++j){
        const int col = bn*BN + wc*(BUNITS*16) + j*16 + li;
        #pragma unroll
        for (int r = 0; r < 4; ++r)
          C[(size_t)(srow + r)*DIM + col] = acc[i][j][r];
      }
    }
  } else {
    #pragma unroll
    for (int i = 0; i < 8; ++i){
      const int srow0 = bm*256 + wr*128 + i*16 + lg*4;
      #pragma unroll
      for (int j = 0; j < BUNITS; ++j){
        const int fc0 = bn*BN + wc*(BUNITS*16) + j*16;   // frag base col (16-aligned)
        const int col = fc0 + li;
        if (fc0 < 5120){                   // Q (cols<4096) or K: fused RoPE
          u16* C  = (fc0 < 4096) ? (u16*)C0 : (u16*)C1;
          const int ldc  = (fc0 < 4096) ? DIM : KVD;
          const int ccol = (fc0 < 4096) ? col : col - 4096;
          const int i4 = ((col & 127) >> 1) << 2;        // boundaries %128==0
          #pragma unroll
          for (int r = 0; r < 4; ++r){
            const float v = acc[i][j][r];
            const float p = __shfl_xor(v, 1);            // partner col (li^1)
            const int srow = srow0 + r;
            const float cs = rf[(size_t)srow*256 + i4];
            const float sn = rf[(size_t)srow*256 + i4 + 1];
            const float o = (col & 1) ? (v*cs + p*sn) : (v*cs - p*sn);
            C[(size_t)srow*ldc + ccol] = f2bf(o);
          }
        } else {                           // V -> transposed write Vt[1024][2048]
          u16* C = (u16*)C2;
          ushort4 o;
          o.x = f2bf(acc[i][j][0]); o.y = f2bf(acc[i][j][1]);
          o.z = f2bf(acc[i][j][2]); o.w = f2bf(acc[i][j][3]);
          *(ushort4*)&C[(size_t)(col - 5120)*SEQ + srow0] = o;
        }
      }
    }
  }
}

// ---------------- causal GQA flash attention ---------------------------------
// 1D grid 1024, longest-qt blocks first: qt = 31 - bid/32, h = bid%32.
// 4 waves; wave w owns q rows [qt*64+16w, +16). Swapped QK^T (mfma(K,Q)) so
// each lane owns one full q-row (q = li): in-lane softmax + 2-shfl reduce.
// K/V double-buffered in LDS, next tile staged before compute (2-phase T3).
__global__ __launch_bounds__(256) void flash_attn(const u16* __restrict__ Q,
                                                  const u16* __restrict__ Kg,
                                                  const u16* __restrict__ Vt,
                                                  u16* __restrict__ O){
  __shared__ bf16x8 smK[2][64*16];              // [64 rows][16 slots], swizzled; 2x16KB
  __shared__ bf16x8 smV[2][128*8];              // [128 rows][8 slots], swizzled; 2x16KB
  __shared__ __align__(16) u16 smP[4][16*64];   // per-wave P, XOR-swizzled 16B chunks; 8KB
  const int bid = blockIdx.x;
  const int h  = bid & 31;
  const int qt = 31 - (bid >> 5);
  const int g  = h >> 2;
  const int t = threadIdx.x, w = t >> 6, l = t & 63;
  const int lg = l >> 4, li = l & 15;

  bf16x8 qf[4];                                  // Q row (w*16+li), d-chunks
  {
    const u16* qrow = Q + (size_t)(qt*64 + w*16 + li)*DIM + h*HD;
    #pragma unroll
    for (int kc = 0; kc < 4; ++kc)
      qf[kc] = *(const bf16x8*)(qrow + kc*32 + lg*8);
  }
  f32x4 accO[8] = {};
  float mrun = -1e30f, lsum = 0.f;
  const float SC = 0.08838834764831845f * 1.4426950408889634f;  // scale * log2(e)

  const int ksrow = t >> 4, ksslot = t & 15;  // K staging: 256B rows, 16 slots
  const int vsrow = t >> 3, vsslot = t & 7;   // V staging: 128B rows, 8 slots

  auto stage = [&](int kt, int b){
    #pragma unroll
    for (int j = 0; j < 4; ++j){
      const int krow = j*16 + ksrow;
      const int ksl = (ksslot & 8) | ((ksslot ^ (krow & 7)) & 7);
      gl_lds16(Kg + (size_t)(kt*64 + krow)*KVD + g*HD + ksl*8, (char*)&smK[b][0] + j*4096 + w*1024);
      const int vrow = j*32 + vsrow;
      const int vsl = (vsslot ^ (vrow & 7)) & 7;
      gl_lds16(Vt + (size_t)(g*HD + vrow)*SEQ + kt*64 + vsl*8, (char*)&smV[b][0] + j*4096 + w*1024);
    }
  };

  stage(0, 0);
  int buf = 0;
  u16* pw = &smP[w][0];

  for (int kt = 0; kt <= qt; ++kt){
    __syncthreads();                      // implicit vmcnt(0): tile-kt stage done
    if (kt < qt) stage(kt + 1, buf ^ 1);  // overlap next stage with this compute

    // S^T = K Q^T : lane holds S[kk = nj*16+lg*4+r][q = li]
    f32x4 sacc[4] = {};
    #pragma unroll
    for (int kc = 0; kc < 4; ++kc){
      #pragma unroll
      for (int nj = 0; nj < 4; ++nj){
        const int R = nj*16 + li;
        int sl = lg + 4*kc;
        sl = (sl & 8) | ((sl ^ (R & 7)) & 7);
        sacc[nj] = __builtin_amdgcn_mfma_f32_16x16x32_bf16(smK[buf][R*16 + sl], qf[kc], sacc[nj], 0, 0, 0);
      }
    }
    float p[4][4];
    #pragma unroll
    for (int nj = 0; nj < 4; ++nj)
      #pragma unroll
      for (int r = 0; r < 4; ++r)
        p[nj][r] = sacc[nj][r] * SC;
    if (kt == qt){                         // mask only on the diagonal tile
      const int qloc = w*16 + li;
      #pragma unroll
      for (int nj = 0; nj < 4; ++nj)
        #pragma unroll
        for (int r = 0; r < 4; ++r)
          if (nj*16 + lg*4 + r > qloc) p[nj][r] = -1e30f;
    }
    // online softmax, row q=li fully in this lane (16 vals) + lanes l^16,l^32
    float mx = p[0][0];
    #pragma unroll
    for (int nj = 0; nj < 4; ++nj)
      #pragma unroll
      for (int r = 0; r < 4; ++r) mx = fmaxf(mx, p[nj][r]);
    mx = fmaxf(mx, __shfl_xor(mx, 16));
    mx = fmaxf(mx, __shfl_xor(mx, 32));
    const float mnew = fmaxf(mrun, mx);
    const float alpha = exp2f(mrun - mnew);
    float s = 0.f;
    #pragma unroll
    for (int nj = 0; nj < 4; ++nj)
      #pragma unroll
      for (int r = 0; r < 4; ++r){ p[nj][r] = exp2f(p[nj][r] - mnew); s += p[nj][r]; }
    s += __shfl_xor(s, 16);
    s += __shfl_xor(s, 32);
    lsum = lsum * alpha + s;
    mrun = mnew;
    // broadcast alpha to accO's rows (q = lg*4+r held by lane li' = lg*4+r)
    float al[4];
    #pragma unroll
    for (int r = 0; r < 4; ++r) al[r] = __shfl(alpha, (l & 48) | (lg*4 + r));
    #pragma unroll
    for (int dj = 0; dj < 8; ++dj)
      #pragma unroll
      for (int r = 0; r < 4; ++r) accO[dj][r] *= al[r];
    // write P (row q=li, kk consecutive per write): 4x 8B swizzled ds_write
    #pragma unroll
    for (int nj = 0; nj < 4; ++nj){
      const int c = nj*2 + (lg >> 1);
      uint2 v; v.x = pack2bf(p[nj][0], p[nj][1]); v.y = pack2bf(p[nj][2], p[nj][3]);
      *(uint2*)((char*)pw + li*128 + ((c ^ (li & 7)) << 4) + ((lg & 1) << 3)) = v;
    }
    // O += P V   (A-frag: P row li, kk = kc2*32+lg*8+j; B-frag: Vt row d)
    #pragma unroll
    for (int kc2 = 0; kc2 < 2; ++kc2){
      const bf16x8 pf = *(const bf16x8*)((char*)pw + li*128 + (((kc2*4 + lg) ^ (li & 7)) << 4));
      #pragma unroll
      for (int dj = 0; dj < 8; ++dj){
        const int R = dj*16 + li;
        const bf16x8 vf = smV[buf][R*8 + ((lg + 4*kc2) ^ (R & 7))];
        accO[dj] = __builtin_amdgcn_mfma_f32_16x16x32_bf16(pf, vf, accO[dj], 0, 0, 0);
      }
    }
    buf ^= 1;
  }
  // epilogue: divide by row sum (row q=lg*4+r), write
  float linv[4];
  #pragma unroll
  for (int r = 0; r < 4; ++r) linv[r] = 1.f / __shfl(lsum, (l & 48) | (lg*4 + r));
  #pragma unroll
  for (int dj = 0; dj < 8; ++dj)
    #pragma unroll
    for (int r = 0; r < 4; ++r)
      O[(size_t)(qt*64 + w*16 + lg*4 + r)*DIM + h*HD + dj*16 + li] = f2bf(accO[dj][r] * linv[r]);
}

// -----------------------------------------------------------------------------
extern "C" void kernel_launch(void* const* d_in, const int* in_sizes, int n_in,
                              void* d_out, int out_size, void* d_ws, size_t ws_size,
                              hipStream_t stream){
  const float* x  = (const float*)d_in[0];
  const float* wq = (const float*)d_in[1];
  const float* wk = (const float*)d_in[2];
  const float* wv = (const float*)d_in[3];
  const float* wo = (const float*)d_in[4];
  const float* rf = (const float*)d_in[5];
  // d_in[6] = start_pos (unused by the reference)
  float* out = (float*)d_out;

  char* ws = (char*)d_ws;
  size_t off = 0;
  auto alloc = [&](size_t nbytes){ void* p = ws + off; off += (nbytes + 255) & ~(size_t)255; return p; };
  u16* xb  = (u16*)alloc((size_t)SEQ*DIM*2);
  u16* wqb = (u16*)alloc((size_t)DIM*DIM*2);   // wqb/wkb/wvb contiguous => B[6144][4096]
  u16* wkb = (u16*)alloc((size_t)KVD*DIM*2);
  u16* wvb = (u16*)alloc((size_t)KVD*DIM*2);
  u16* wob = (u16*)alloc((size_t)DIM*DIM*2);
  u16* Qb  = (u16*)alloc((size_t)SEQ*DIM*2);
  u16* K8  = (u16*)alloc((size_t)SEQ*KVD*2);
  u16* Vtr = (u16*)alloc((size_t)KVD*SEQ*2);
  u16* AO  = (u16*)alloc((size_t)SEQ*DIM*2);
  float* P1 = (float*)wqb;   // reuse: wqb is dead after the QKV GEMM (32 MB)

  cvt_all<<<49152, 256, 0, stream>>>(x, wq, wk, wv, wo, xb, wqb, wkb, wvb, wob);

  // Fused QKV projection + RoPE + V^T (256 blocks = 8bm x 32bn, BN=192)
  gemmP<3, 0><<<256, 512, 0, stream>>>(xb, wqb, Qb, K8, Vtr, rf, nullptr);

  flash_attn<<<SEQ/64 * NH, 256, 0, stream>>>(Qb, K8, Vtr, AO);

  // O projection, split-K=2 (256 blocks = 8bm x 2ks x 16bn, BN=256)
  gemmP<4, 1><<<256, 512, 0, stream>>>(AO, wob, out, nullptr, nullptr, nullptr, P1);
  add_f32<<<8192, 256, 0, stream>>>(out, P1);
}